// Round 1
// baseline (825.386 us; speedup 1.0000x reference)
//
#include <hip/hip_runtime.h>
#include <math.h>

// ---------------------------------------------------------------------------
// GCN: x[N,128] -> conv1(W1[128,32]) -> relu -> conv2(W2[32,16]) -> fc heads
// Outputs (concat): r[N], x1f[N]
// ---------------------------------------------------------------------------

#define TPB 256

__device__ __forceinline__ float atomAddF(float* p, float v) {
    return unsafeAtomicAdd(p, v);   // native global_atomic_add_f32 on gfx950
}

// deg[dst] += w  (self-loop +1 added later)
__global__ __launch_bounds__(TPB) void deg_kernel(const int* __restrict__ dst,
                                                  const float* __restrict__ ew,
                                                  float* __restrict__ deg, int E) {
    int e = blockIdx.x * TPB + threadIdx.x;
    if (e < E) atomAddF(&deg[dst[e]], ew[e]);
}

// deg -> dinv = 1/sqrt(deg+1)  (in place)
__global__ __launch_bounds__(TPB) void dinv_kernel(float* __restrict__ deg, int N) {
    int i = blockIdx.x * TPB + threadIdx.x;
    if (i < N) deg[i] = 1.0f / sqrtf(deg[i] + 1.0f);
}

// h[N,32] = x[N,128] @ W[128,32].  Block: 32 nodes, 256 threads.
// thread = (node_local = tid/8, out_group = (tid%8)*4) -> 4 outputs each.
__global__ __launch_bounds__(TPB) void gemm1_kernel(const float* __restrict__ x,
                                                    const float* __restrict__ W,
                                                    float* __restrict__ h, int N) {
    __shared__ float Ws[128 * 32];     // 16 KB
    __shared__ float xs[32 * 129];     // padded stride 129 to kill bank conflicts
    const int tid = threadIdx.x;
    const int nb  = blockIdx.x * 32;

    // load W (4096 floats = 1024 float4)
    const float4* W4  = (const float4*)W;
    float4*       Ws4 = (float4*)Ws;
#pragma unroll
    for (int i = 0; i < 4; ++i) Ws4[tid + i * 256] = W4[tid + i * 256];

    // load 32 x-rows (contiguous 4096 floats), write with padded stride
#pragma unroll
    for (int i = 0; i < 4; ++i) {
        int idx  = tid + i * 256;      // float4 index within the 32x128 tile
        int node = idx >> 5;           // 32 float4 per row
        int col4 = idx & 31;
        if (nb + node < N) {
            float4 v = ((const float4*)(x + (size_t)nb * 128))[idx];
            float* p = &xs[node * 129 + col4 * 4];
            p[0] = v.x; p[1] = v.y; p[2] = v.z; p[3] = v.w;
        }
    }
    __syncthreads();

    const int nl = tid >> 3;           // 0..31
    const int og = (tid & 7) * 4;      // 0,4,...,28
    float a0 = 0.f, a1 = 0.f, a2 = 0.f, a3 = 0.f;
#pragma unroll 8
    for (int k = 0; k < 128; ++k) {
        float xv = xs[nl * 129 + k];
        const float* wp = &Ws[k * 32 + og];
        a0 = fmaf(xv, wp[0], a0);
        a1 = fmaf(xv, wp[1], a1);
        a2 = fmaf(xv, wp[2], a2);
        a3 = fmaf(xv, wp[3], a3);
    }
    int node = nb + nl;
    if (node < N) {
        float* out = &h[(size_t)node * 32 + og];
        out[0] = a0; out[1] = a1; out[2] = a2; out[3] = a3;
    }
}

// per (edge, feature f<32): agg[dst*32+f] += dinv[src]*w*dinv[dst] * h[src*32+f]
__global__ __launch_bounds__(TPB) void scatter32_kernel(const int* __restrict__ src,
                                                        const int* __restrict__ dst,
                                                        const float* __restrict__ ew,
                                                        const float* __restrict__ dinv,
                                                        const float* __restrict__ h,
                                                        float* __restrict__ agg, int E) {
    int tid = blockIdx.x * TPB + threadIdx.x;   // < E*32 = 102.4M, fits int
    int e = tid >> 5;
    int f = tid & 31;
    if (e >= E) return;
    int s = src[e], d = dst[e];
    float norm = dinv[s] * ew[e] * dinv[d];
    float v = norm * h[(size_t)s * 32 + f];
    atomAddF(&agg[(size_t)d * 32 + f], v);
}

// per (edge, feature f<16)
__global__ __launch_bounds__(TPB) void scatter16_kernel(const int* __restrict__ src,
                                                        const int* __restrict__ dst,
                                                        const float* __restrict__ ew,
                                                        const float* __restrict__ dinv,
                                                        const float* __restrict__ h,
                                                        float* __restrict__ agg, int E) {
    int tid = blockIdx.x * TPB + threadIdx.x;   // < E*16
    int e = tid >> 4;
    int f = tid & 15;
    if (e >= E) return;
    int s = src[e], d = dst[e];
    float norm = dinv[s] * ew[e] * dinv[d];
    float v = norm * h[(size_t)s * 16 + f];
    atomAddF(&agg[(size_t)d * 16 + f], v);
}

// agg1 = relu(agg1 + h1*invdeg + b1)   (float4 over N*32)
__global__ __launch_bounds__(TPB) void combine1_kernel(float* __restrict__ agg,
                                                       const float* __restrict__ h,
                                                       const float* __restrict__ dinv,
                                                       const float* __restrict__ b, int N) {
    int idx = blockIdx.x * TPB + threadIdx.x;   // over N*8 float4
    if (idx >= N * 8) return;
    int i  = idx >> 3;
    int fb = (idx & 7) * 4;
    float di  = dinv[i];
    float inv = di * di;                         // 1/deg
    float4 a  = ((const float4*)agg)[idx];
    float4 hv = ((const float4*)h)[idx];
    a.x = fmaxf(fmaf(hv.x, inv, a.x) + b[fb + 0], 0.f);
    a.y = fmaxf(fmaf(hv.y, inv, a.y) + b[fb + 1], 0.f);
    a.z = fmaxf(fmaf(hv.z, inv, a.z) + b[fb + 2], 0.f);
    a.w = fmaxf(fmaf(hv.w, inv, a.w) + b[fb + 3], 0.f);
    ((float4*)agg)[idx] = a;
}

// h2[N,16] = h[N,32] @ W2[32,16]; thread per (node, f)
__global__ __launch_bounds__(TPB) void gemm2_kernel(const float* __restrict__ h,
                                                    const float* __restrict__ W,
                                                    float* __restrict__ out, int N) {
    __shared__ float Ws[32 * 16];
    int tid = threadIdx.x;
    if (tid < 128) ((float4*)Ws)[tid] = ((const float4*)W)[tid];
    __syncthreads();
    int idx  = blockIdx.x * TPB + tid;
    int node = idx >> 4;
    int f    = idx & 15;
    if (node >= N) return;
    const float* hr = &h[(size_t)node * 32];
    float acc = 0.f;
#pragma unroll
    for (int k = 0; k < 32; ++k) acc = fmaf(hr[k], Ws[k * 16 + f], acc);
    out[(size_t)node * 16 + f] = acc;
}

// x2 = agg2 + h2*invdeg + b2; x1f = x2.fc1_w + fc1_b; c = sigmoid(x1f);
// r = h.fc2_w[0:32] + c*fc2_w[32] + fc2_b.  out[i]=r, out[N+i]=x1f
__global__ __launch_bounds__(TPB) void final_kernel(const float* __restrict__ agg2,
                                                    const float* __restrict__ h2,
                                                    const float* __restrict__ hbuf,
                                                    const float* __restrict__ dinv,
                                                    const float* __restrict__ b2,
                                                    const float* __restrict__ fc1_w,
                                                    const float* __restrict__ fc1_b,
                                                    const float* __restrict__ fc2_w,
                                                    const float* __restrict__ fc2_b,
                                                    float* __restrict__ out, int N) {
    int i = blockIdx.x * TPB + threadIdx.x;
    if (i >= N) return;
    float di  = dinv[i];
    float inv = di * di;
    float x1f = fc1_b[0];
#pragma unroll
    for (int f = 0; f < 16; ++f) {
        float x2 = fmaf(h2[(size_t)i * 16 + f], inv, agg2[(size_t)i * 16 + f]) + b2[f];
        x1f = fmaf(x2, fc1_w[f], x1f);
    }
    float c = 1.0f / (1.0f + expf(-x1f));
    float r = fmaf(c, fc2_w[32], fc2_b[0]);
#pragma unroll
    for (int k = 0; k < 32; ++k) r = fmaf(hbuf[(size_t)i * 32 + k], fc2_w[k], r);
    out[i]     = r;
    out[N + i] = x1f;
}

extern "C" void kernel_launch(void* const* d_in, const int* in_sizes, int n_in,
                              void* d_out, int out_size, void* d_ws, size_t ws_size,
                              hipStream_t stream) {
    const float* x     = (const float*)d_in[0];
    const int*   ei    = (const int*)d_in[1];
    const float* ew    = (const float*)d_in[2];
    const float* W1    = (const float*)d_in[3];
    const float* b1    = (const float*)d_in[4];
    const float* W2    = (const float*)d_in[5];
    const float* b2    = (const float*)d_in[6];
    const float* fc1_w = (const float*)d_in[7];
    const float* fc1_b = (const float*)d_in[8];
    const float* fc2_w = (const float*)d_in[9];
    const float* fc2_b = (const float*)d_in[10];

    const int N = in_sizes[0] / 128;
    const int E = in_sizes[2];
    const int* src = ei;
    const int* dst = ei + E;

    // workspace layout (floats): deg/dinv[N] | h1[32N] | agg1[32N] | h2[16N] | agg2[16N]
    float* ws   = (float*)d_ws;
    float* deg  = ws;
    float* h1   = deg  + N;
    float* agg1 = h1   + (size_t)32 * N;
    float* h2   = agg1 + (size_t)32 * N;
    float* agg2 = h2   + (size_t)16 * N;

    hipMemsetAsync(deg,  0, (size_t)N * sizeof(float), stream);
    hipMemsetAsync(agg1, 0, (size_t)N * 32 * sizeof(float), stream);
    hipMemsetAsync(agg2, 0, (size_t)N * 16 * sizeof(float), stream);

    deg_kernel<<<(E + TPB - 1) / TPB, TPB, 0, stream>>>(dst, ew, deg, E);
    gemm1_kernel<<<(N + 31) / 32, TPB, 0, stream>>>(x, W1, h1, N);
    dinv_kernel<<<(N + TPB - 1) / TPB, TPB, 0, stream>>>(deg, N);

    long long t1 = (long long)E * 32;
    scatter32_kernel<<<(unsigned)((t1 + TPB - 1) / TPB), TPB, 0, stream>>>(
        src, dst, ew, deg, h1, agg1, E);
    combine1_kernel<<<(N * 8 + TPB - 1) / TPB, TPB, 0, stream>>>(agg1, h1, deg, b1, N);

    gemm2_kernel<<<((N * 16) + TPB - 1) / TPB, TPB, 0, stream>>>(agg1, W2, h2, N);

    long long t2 = (long long)E * 16;
    scatter16_kernel<<<(unsigned)((t2 + TPB - 1) / TPB), TPB, 0, stream>>>(
        src, dst, ew, deg, h2, agg2, E);

    final_kernel<<<(N + TPB - 1) / TPB, TPB, 0, stream>>>(
        agg2, h2, agg1, deg, b2, fc1_w, fc1_b, fc2_w, fc2_b, (float*)d_out, N);
}